// Round 21
// baseline (145.990 us; speedup 1.0000x reference)
//
#include <hip/hip_runtime.h>
#include <hip/hip_fp16.h>

#define N_NODES 100000
#define N_EDGES 1600000
#define IN_DIM  256
#define OUT_DIM 128

#define BROWS  256                     // rows per bucket
#define NBKT   391                     // ceil(100000/256)
#define CAP    4608                    // per-bucket capacity (mean 4096 + 8 sigma)
#define CHUNK  8192                    // edges per bin block
#define NBLK   196                     // ceil(1600000/8192)
#define DCAP   6144                    // LDS sort capacity

#define BMT    32                      // gemm tile rows
#define NTILE  (N_NODES / BMT)         // 3125 exact
#define TPB    4
#define NGBLK  ((NTILE + TPB - 1) / TPB)   // 782
#define BUFSZ  (BMT * 512)             // 16 KB
#define TPC    8                       // tiles per convert block
#define NCVT   ((NTILE + TPC - 1) / TPC)   // 391

typedef __attribute__((ext_vector_type(8))) short short8;
typedef __attribute__((ext_vector_type(4))) float f32x4;
typedef __attribute__((ext_vector_type(2))) float f32x2;

__device__ __forceinline__ unsigned short f2bf(float f) {
    unsigned int u = __float_as_uint(f);
    u += 0x7FFFu + ((u >> 16) & 1u);
    return (unsigned short)(u >> 16);
}
__device__ __forceinline__ float bf2f(unsigned int u16) {
    return __uint_as_float(u16 << 16);
}
__device__ __forceinline__ short8 pack8(float4 a, float4 b) {
    short8 s;
    s[0] = (short)f2bf(a.x); s[1] = (short)f2bf(a.y);
    s[2] = (short)f2bf(a.z); s[3] = (short)f2bf(a.w);
    s[4] = (short)f2bf(b.x); s[5] = (short)f2bf(b.y);
    s[6] = (short)f2bf(b.z); s[7] = (short)f2bf(b.w);
    return s;
}

// async 16B global -> LDS (wave-uniform LDS base + lane*16 by HW)
__device__ __forceinline__ void gload16(const void* g, void* l) {
    __builtin_amdgcn_global_load_lds(
        (const __attribute__((address_space(1))) unsigned int*)g,
        (__attribute__((address_space(3))) unsigned int*)l, 16, 0, 0);
}

// ---------------------------------------------------------------------------
// W -> bf16 + zero bcnt.
// ---------------------------------------------------------------------------
__global__ __launch_bounds__(256) void w_to_bf16(const float* __restrict__ W,
                                                 unsigned short* __restrict__ Wb,
                                                 int* __restrict__ bcnt) {
    int i = blockIdx.x * 256 + threadIdx.x;
    if (i < OUT_DIM * IN_DIM) Wb[i] = f2bf(W[i]);
    if (blockIdx.x == 0)
        for (int b = threadIdx.x; b < NBKT; b += 256) bcnt[b] = 0;
}

// ---------------------------------------------------------------------------
// D1: blocks [0,NBLK) = bin pass; blocks [NBLK,NBLK+NCVT) = x -> bf16 with
// the gemm LDS swizzle BAKED into the global layout (rule #21: pre-swizzled
// source + linear global_load_lds + swizzled ds_read).
// x_swz tile t (16 KB): byte (lr*512 + col*2) ^ ((lr&7)<<4), lr=row&31.
// ---------------------------------------------------------------------------
__global__ __launch_bounds__(512) void cvt_bin(const float* __restrict__ x,
                                               unsigned short* __restrict__ xswz,
                                               const int* __restrict__ erow,
                                               const int* __restrict__ ecol,
                                               const float* __restrict__ eval,
                                               int* __restrict__ bcnt,
                                               int2* __restrict__ gbuf) {
    __shared__ int shm[3 * NBKT];
    const int tid = threadIdx.x;

    if (blockIdx.x < NBLK) {
        // bin role (R19-proven)
        int* h    = shm;
        int* gpos = h + NBKT;
        int* rcur = gpos + NBKT;
        for (int i = tid; i < NBKT; i += 512) { h[i] = 0; rcur[i] = 0; }
        __syncthreads();
        const int e0 = blockIdx.x * CHUNK;
        for (int i = tid; i < CHUNK; i += 512) {
            int e = e0 + i;
            if (e < N_EDGES) atomicAdd(&h[erow[e] >> 8], 1);
        }
        __syncthreads();
        for (int i = tid; i < NBKT; i += 512)
            gpos[i] = h[i] ? (i * CAP + atomicAdd(&bcnt[i], h[i])) : 0;
        __syncthreads();
        for (int i = tid; i < CHUNK; i += 512) {
            int e = e0 + i;
            if (e < N_EDGES) {
                int r = erow[e];
                int b = r >> 8;
                unsigned int vb  = __half_as_ushort(__float2half(eval[e]));
                unsigned int rec = (vb << 17) | (unsigned int)ecol[e];
                int pos = gpos[b] + atomicAdd(&rcur[b], 1);
                gbuf[pos] = make_int2((int)rec, r);
            }
        }
        return;
    }

    // convert role: 8 tiles per block; thread -> row=tid>>4, 16-col chunk
    const int tb  = (blockIdx.x - NBLK) * TPC;
    const int row = tid >> 4;
    const int c0  = (tid & 15) * 16;
    const int sb  = (row & 7) << 4;
    const int o0  = (row * 512 + c0 * 2) ^ sb;
    const int o1  = (row * 512 + (c0 + 8) * 2) ^ sb;
#pragma unroll
    for (int q = 0; q < TPC; ++q) {
        const int ti = tb + q;
        if (ti < NTILE) {
            const float4* src = (const float4*)(x + (size_t)(ti * BMT + row) * IN_DIM + c0);
            float4 f0 = src[0], f1 = src[1], f2 = src[2], f3 = src[3];
            char* dst = (char*)xswz + (size_t)ti * 16384;
            *(short8*)(dst + o0) = pack8(f0, f1);
            *(short8*)(dst + o1) = pack8(f2, f3);
        }
    }
}

// ---------------------------------------------------------------------------
// D2: pure GEMM with async global_load_lds double-buffer (m97 pattern):
// barrier -> issue next tile's DMA -> compute current (loads land under it).
// ---------------------------------------------------------------------------
__global__ __launch_bounds__(512) void gemm_async(const unsigned short* __restrict__ xswz,
                                                  const unsigned short* __restrict__ Wb,
                                                  unsigned short* __restrict__ hb) {
    __shared__ unsigned short xs[2 * BMT * 256];   // 32 KB
    const int tid  = threadIdx.x;
    const int t0   = blockIdx.x * TPB;
    const int wid  = tid >> 6;
    const int lane = tid & 63;
    const int l15  = lane & 15;
    const int g8   = (lane >> 4) * 8;
    const int col  = wid * 16 + l15;
    const int sw   = (l15 & 7) << 4;
    char* lb = (char*)xs;
    const char* xb = (const char*)xswz;

    short8 bfr[8];
    const unsigned short* wrow = Wb + (size_t)col * IN_DIM + g8;
#pragma unroll
    for (int kk = 0; kk < 8; ++kk)
        bfr[kk] = *(const short8*)(wrow + kk * 32);

    // prologue: DMA tile t0 -> buf0 (2 x 16B per thread; 1 KB per wave-call)
    {
        const int ti = (t0 < NTILE) ? t0 : 0;
        const char* g = xb + (size_t)ti * 16384 + wid * 2048 + lane * 16;
        char* l = lb + wid * 2048;               // wave-uniform
        gload16(g, l);
        gload16(g + 1024, l + 1024);
    }

#pragma unroll
    for (int i = 0; i < TPB; ++i) {
        __syncthreads();   // vmcnt(0): buf(i&1) DMA complete + visible

        // issue next tile's DMA AFTER the barrier -> lands under compute
        if (i + 1 < TPB) {
            const int tn = (t0 + i + 1 < NTILE) ? (t0 + i + 1) : 0;
            const char* g = xb + (size_t)tn * 16384 + wid * 2048 + lane * 16;
            char* l = lb + ((i + 1) & 1) * BUFSZ + wid * 2048;
            gload16(g, l);
            gload16(g + 1024, l + 1024);
        }

        const int ti = t0 + i;
        if (ti < NTILE) {
            const char* cb = lb + (i & 1) * BUFSZ;
            short8 a0[8], a1[8];
#pragma unroll
            for (int kk = 0; kk < 8; ++kk) {
                a0[kk] = *(const short8*)(cb + ((l15 * 512 + (kk * 32 + g8) * 2) ^ sw));
                a1[kk] = *(const short8*)(cb + (((l15 + 16) * 512 + (kk * 32 + g8) * 2) ^ sw));
            }
            f32x4 acc0 = {0.f, 0.f, 0.f, 0.f}, acc1 = {0.f, 0.f, 0.f, 0.f};
#pragma unroll
            for (int kk = 0; kk < 8; ++kk) {
                acc0 = __builtin_amdgcn_mfma_f32_16x16x32_bf16(a0[kk], bfr[kk], acc0, 0, 0, 0);
                acc1 = __builtin_amdgcn_mfma_f32_16x16x32_bf16(a1[kk], bfr[kk], acc1, 0, 0, 0);
            }
            const int rb0 = ti * BMT + (lane >> 4) * 4;
            const int rb1 = rb0 + 16;
#pragma unroll
            for (int q = 0; q < 4; ++q) {
                hb[(size_t)(rb0 + q) * OUT_DIM + col] = f2bf(acc0[q]);
                hb[(size_t)(rb1 + q) * OUT_DIM + col] = f2bf(acc1[q]);
            }
        }
    }
}

// ---------------------------------------------------------------------------
// R19-proven fused gemm+bin (fallback when ws can't hold x_swz).
// ---------------------------------------------------------------------------
__global__ __launch_bounds__(512) void gemm_bin(const float* __restrict__ x,
                                                const unsigned short* __restrict__ Wb,
                                                unsigned short* __restrict__ hb,
                                                const int* __restrict__ erow,
                                                const int* __restrict__ ecol,
                                                const float* __restrict__ eval,
                                                int* __restrict__ bcnt,
                                                int2* __restrict__ gbuf) {
    __shared__ unsigned short xs[2 * BMT * 256];
    const int tid = threadIdx.x;

    if (blockIdx.x < NBLK) {
        int* h    = (int*)xs;
        int* gpos = h + NBKT;
        int* rcur = gpos + NBKT;
        for (int i = tid; i < NBKT; i += 512) { h[i] = 0; rcur[i] = 0; }
        __syncthreads();
        const int e0 = blockIdx.x * CHUNK;
        for (int i = tid; i < CHUNK; i += 512) {
            int e = e0 + i;
            if (e < N_EDGES) atomicAdd(&h[erow[e] >> 8], 1);
        }
        __syncthreads();
        for (int i = tid; i < NBKT; i += 512)
            gpos[i] = h[i] ? (i * CAP + atomicAdd(&bcnt[i], h[i])) : 0;
        __syncthreads();
        for (int i = tid; i < CHUNK; i += 512) {
            int e = e0 + i;
            if (e < N_EDGES) {
                int r = erow[e];
                int b = r >> 8;
                unsigned int vb  = __half_as_ushort(__float2half(eval[e]));
                unsigned int rec = (vb << 17) | (unsigned int)ecol[e];
                int pos = gpos[b] + atomicAdd(&rcur[b], 1);
                gbuf[pos] = make_int2((int)rec, r);
            }
        }
        return;
    }

    const int g    = blockIdx.x - NBLK;
    const int t0   = g * TPB;
    const int wid  = tid >> 6;
    const int lane = tid & 63;
    const int l15  = lane & 15;
    const int g8   = (lane >> 4) * 8;
    const int col  = wid * 16 + l15;
    const int sw   = (l15 & 7) << 4;
    char* lb = (char*)xs;
    const int srow = tid >> 4;
    const int ca   = (tid & 15) * 8;
    const int swr  = (srow & 7) << 4;
    const int wbA  = (srow * 512 + ca * 2) ^ swr;
    const int wbB  = (srow * 512 + (ca + 128) * 2) ^ swr;

    short8 bfr[8];
    const unsigned short* wrow = Wb + (size_t)col * IN_DIM + g8;
#pragma unroll
    for (int kk = 0; kk < 8; ++kk)
        bfr[kk] = *(const short8*)(wrow + kk * 32);

    {
        const int ti = t0;
        const int gr = (ti < NTILE) ? (ti * BMT + srow) : srow;
        const float4* sA = (const float4*)(x + (size_t)gr * IN_DIM + ca);
        const float4* sB = (const float4*)(x + (size_t)gr * IN_DIM + ca + 128);
        float4 f0 = sA[0], f1 = sA[1], f2 = sB[0], f3 = sB[1];
        *(short8*)(lb + wbA) = pack8(f0, f1);
        *(short8*)(lb + wbB) = pack8(f2, f3);
    }

#pragma unroll
    for (int i = 0; i < TPB; ++i) {
        float4 q0, q1, q2, q3;
        if (i + 1 < TPB) {
            const int ti = t0 + i + 1;
            const int gr = (ti < NTILE) ? (ti * BMT + srow) : srow;
            const float4* sA = (const float4*)(x + (size_t)gr * IN_DIM + ca);
            const float4* sB = (const float4*)(x + (size_t)gr * IN_DIM + ca + 128);
            q0 = sA[0]; q1 = sA[1]; q2 = sB[0]; q3 = sB[1];
        }
        __syncthreads();

        const int ti = t0 + i;
        const char* cb = lb + (i & 1) * BUFSZ;
        short8 a0[8], a1[8];
#pragma unroll
        for (int kk = 0; kk < 8; ++kk) {
            a0[kk] = *(const short8*)(cb + ((l15 * 512 + (kk * 32 + g8) * 2) ^ sw));
            a1[kk] = *(const short8*)(cb + (((l15 + 16) * 512 + (kk * 32 + g8) * 2) ^ sw));
        }
        f32x4 acc0 = {0.f, 0.f, 0.f, 0.f}, acc1 = {0.f, 0.f, 0.f, 0.f};
#pragma unroll
        for (int kk = 0; kk < 8; ++kk) {
            acc0 = __builtin_amdgcn_mfma_f32_16x16x32_bf16(a0[kk], bfr[kk], acc0, 0, 0, 0);
            acc1 = __builtin_amdgcn_mfma_f32_16x16x32_bf16(a1[kk], bfr[kk], acc1, 0, 0, 0);
        }
        if (ti < NTILE) {
            const int rb0 = ti * BMT + (lane >> 4) * 4;
            const int rb1 = rb0 + 16;
#pragma unroll
            for (int q = 0; q < 4; ++q) {
                hb[(size_t)(rb0 + q) * OUT_DIM + col] = f2bf(acc0[q]);
                hb[(size_t)(rb1 + q) * OUT_DIM + col] = f2bf(acc1[q]);
            }
        }
        if (i + 1 < TPB) {
            char* wbuf = lb + ((i + 1) & 1) * BUFSZ;
            *(short8*)(wbuf + wbA) = pack8(q0, q1);
            *(short8*)(wbuf + wbB) = pack8(q2, q3);
        }
    }
}

// ---------------------------------------------------------------------------
// Per-bucket LDS counting sort (R19-proven, 256 thr).
// ---------------------------------------------------------------------------
__global__ __launch_bounds__(256) void sort_bucket(const int2* __restrict__ gbuf,
                                                   const int* __restrict__ bcnt,
                                                   unsigned int* __restrict__ gcsr,
                                                   int* __restrict__ offs,
                                                   int* __restrict__ bend) {
    __shared__ int rh[BROWS], rc[BROWS], tmp[256];
    __shared__ unsigned int lout[DCAP];
    const int b    = blockIdx.x;
    const int base = b * CAP;
    const int cnt  = bcnt[b];
    const int r0   = b * BROWS;
    const int t    = threadIdx.x;

    rh[t] = 0;
    __syncthreads();
    for (int i = t; i < cnt; i += 256)
        atomicAdd(&rh[gbuf[base + i].y - r0], 1);
    __syncthreads();

    int v = rh[t];
    tmp[t] = v;
    __syncthreads();
    for (int d = 1; d < 256; d <<= 1) {
        int a = (t >= d) ? tmp[t - d] : 0;
        __syncthreads();
        tmp[t] += a;
        __syncthreads();
    }
    int ex = tmp[t] - v;
    rc[t] = ex;
    offs[r0 + t] = base + ex;
    if (t == 0) bend[b] = base + cnt;
    __syncthreads();

    if (cnt <= DCAP) {
        for (int i = t; i < cnt; i += 256) {
            int2 rr = gbuf[base + i];
            int p = atomicAdd(&rc[rr.y - r0], 1);
            lout[p] = (unsigned int)rr.x;
        }
        __syncthreads();
        for (int i = t; i < cnt; i += 256)
            gcsr[base + i] = lout[i];
    } else {
        for (int i = t; i < cnt; i += 256) {
            int2 rr = gbuf[base + i];
            int p = atomicAdd(&rc[rr.y - r0], 1);
            gcsr[base + p] = (unsigned int)rr.x;
        }
    }
}

// ---------------------------------------------------------------------------
// Gather (R19-proven): 2 rows/wave, 4 channels/lane, packed FMA.
// ---------------------------------------------------------------------------
__global__ __launch_bounds__(256) void spmm_gather(const unsigned short* __restrict__ hb,
                                                   const int* __restrict__ offs,
                                                   const int* __restrict__ bend,
                                                   const unsigned int* __restrict__ ccv,
                                                   float* __restrict__ out) {
    const int lane = threadIdx.x & 63;
    const int half = lane >> 5;
    const int li   = lane & 31;
    const int r    = blockIdx.x * 8 + (threadIdx.x >> 6) * 2 + half;

    const int js = offs[r];
    const int je = ((r & (BROWS - 1)) == (BROWS - 1)) ? bend[r >> 8] : offs[r + 1];

    f32x2 accA = {0.f, 0.f}, accB = {0.f, 0.f};
    for (int j = js; __any(j < je); j += 8) {
        unsigned int e[8];
        uint2 p[8];
#pragma unroll
        for (int q = 0; q < 8; ++q) {
            int jj = j + q;
            e[q] = ccv[jj < je ? jj : 0];
        }
#pragma unroll
        for (int q = 0; q < 8; ++q)
            p[q] = *(const uint2*)(hb + (size_t)(e[q] & 0x1FFFFu) * OUT_DIM + li * 4);
#pragma unroll
        for (int q = 0; q < 8; ++q) {
            float v = (j + q < je)
                    ? __half2float(__ushort_as_half((unsigned short)(e[q] >> 17)))
                    : 0.f;
            f32x2 vv  = {v, v};
            f32x2 h01 = { __uint_as_float(p[q].x << 16),
                          __uint_as_float(p[q].x & 0xFFFF0000u) };
            f32x2 h23 = { __uint_as_float(p[q].y << 16),
                          __uint_as_float(p[q].y & 0xFFFF0000u) };
            accA = __builtin_elementwise_fma(vv, h01, accA);
            accB = __builtin_elementwise_fma(vv, h23, accB);
        }
    }
    float4 o = {accA.x, accA.y, accB.x, accB.y};
    *(float4*)(out + (size_t)r * OUT_DIM + li * 4) = o;
}

// ---------------------------------------------------------------------------
// Last-resort fallback: plain gemm + atomic scatter.
// ---------------------------------------------------------------------------
__global__ __launch_bounds__(512) void gemm_plain(const float* __restrict__ x,
                                                  const float* __restrict__ W,
                                                  unsigned short* __restrict__ hb) {
    __shared__ unsigned short xs[2 * BMT * 256];
    const int tid = threadIdx.x;
    const int m0  = blockIdx.x * (2 * BMT);
    char* lb = (char*)xs;
    {
        const int row = tid >> 3;
        const int cs  = (tid & 7) * 32;
        const int gr  = m0 + row;
        if (gr < N_NODES) {
            const float4* src = (const float4*)(x + (size_t)gr * IN_DIM + cs);
#pragma unroll
            for (int i = 0; i < 4; ++i) {
                float4 a = src[2 * i], b = src[2 * i + 1];
                int byt = (row * 512 + (cs + 8 * i) * 2) ^ ((row & 7) << 4);
                *(short8*)(lb + byt) = pack8(a, b);
            }
        } else {
            short8 z = {0, 0, 0, 0, 0, 0, 0, 0};
#pragma unroll
            for (int i = 0; i < 4; ++i) {
                int byt = (row * 512 + (cs + 8 * i) * 2) ^ ((row & 7) << 4);
                *(short8*)(lb + byt) = z;
            }
        }
    }
    __syncthreads();
    const int wid  = tid >> 6;
    const int lane = tid & 63;
    const int l15  = lane & 15;
    const int g8   = (lane >> 4) * 8;
    short8 bfr[8];
    const float* wrowf = W + (size_t)(wid * 16 + l15) * IN_DIM + g8;
#pragma unroll
    for (int kk = 0; kk < 8; ++kk) {
        float4 wa = *(const float4*)(wrowf + kk * 32);
        float4 wb = *(const float4*)(wrowf + kk * 32 + 4);
        bfr[kk] = pack8(wa, wb);
    }
    const int col = wid * 16 + l15;
    const int sw  = (l15 & 7) << 4;
    const char* lbc = (const char*)xs;
#pragma unroll
    for (int rp = 0; rp < 2; ++rp) {
        const int r0 = rp * 32 + l15;
        const int r1 = r0 + 16;
        short8 a0[8], a1[8];
#pragma unroll
        for (int kk = 0; kk < 8; ++kk) {
            a0[kk] = *(const short8*)(lbc + ((r0 * 512 + (kk * 32 + g8) * 2) ^ sw));
            a1[kk] = *(const short8*)(lbc + ((r1 * 512 + (kk * 32 + g8) * 2) ^ sw));
        }
        f32x4 acc0 = {0.f, 0.f, 0.f, 0.f}, acc1 = {0.f, 0.f, 0.f, 0.f};
#pragma unroll
        for (int kk = 0; kk < 8; ++kk) {
            acc0 = __builtin_amdgcn_mfma_f32_16x16x32_bf16(a0[kk], bfr[kk], acc0, 0, 0, 0);
            acc1 = __builtin_amdgcn_mfma_f32_16x16x32_bf16(a1[kk], bfr[kk], acc1, 0, 0, 0);
        }
        const int rb0 = m0 + rp * 32 + (lane >> 4) * 4;
        const int rb1 = rb0 + 16;
#pragma unroll
        for (int i = 0; i < 4; ++i) {
            if (rb0 + i < N_NODES) hb[(size_t)(rb0 + i) * OUT_DIM + col] = f2bf(acc0[i]);
            if (rb1 + i < N_NODES) hb[(size_t)(rb1 + i) * OUT_DIM + col] = f2bf(acc1[i]);
        }
    }
}

__global__ __launch_bounds__(256) void spmm_scatter(const unsigned short* __restrict__ hb,
                                                    const int* __restrict__ erow,
                                                    const int* __restrict__ ecol,
                                                    const float* __restrict__ eval,
                                                    float* __restrict__ out) {
    const int lane = threadIdx.x & 63;
    const int eloc = threadIdx.x >> 6;
    const int stride = gridDim.x * 4;
    for (int e = blockIdx.x * 4 + eloc; e < N_EDGES; e += stride) {
        const int r = erow[e];
        const int c = ecol[e];
        const float v = eval[e];
        unsigned int p = *(const unsigned int*)(hb + (size_t)c * OUT_DIM + lane * 2);
        float* o = out + (size_t)r * OUT_DIM + lane * 2;
        unsafeAtomicAdd(o + 0, v * bf2f(p & 0xFFFFu));
        unsafeAtomicAdd(o + 1, v * bf2f(p >> 16));
    }
}

extern "C" void kernel_launch(void* const* d_in, const int* in_sizes, int n_in,
                              void* d_out, int out_size, void* d_ws, size_t ws_size,
                              hipStream_t stream) {
    const float* x    = (const float*)d_in[0];
    const float* W    = (const float*)d_in[1];
    const int*   erow = (const int*)d_in[2];
    const int*   ecol = (const int*)d_in[3];
    const float* eval = (const float*)d_in[4];
    float*       out  = (float*)d_out;

    // layout: hb | gbuf | offs | bend | bcnt | Wb | Z
    // Z = x_swz (51.2 MB, full path) with gcsr aliased at its start (sort runs
    //     after gemm has consumed x_swz), or just gcsr (7.2 MB, R19 path).
    const size_t H_ELEMS = (size_t)N_NODES * OUT_DIM;
    unsigned short* hb    = (unsigned short*)d_ws;                        // 25.6 MB
    int2*           gbuf  = (int2*)(hb + H_ELEMS);                        // 14.41 MB
    int*            offs  = (int*)(gbuf + (size_t)NBKT * CAP);            // 400 KB
    int*            bend  = offs + NBKT * BROWS + 8;
    int*            bcnt  = bend + NBKT;
    unsigned short* Wb    = (unsigned short*)(bcnt + NBKT + 8);           // 64 KB
    char*           zraw  = (char*)(Wb + OUT_DIM * IN_DIM);
    char*           Z     = zraw + ((16 - ((size_t)zraw & 15)) & 15);     // 16B align
    unsigned short* xswz  = (unsigned short*)Z;
    unsigned int*   gcsr  = (unsigned int*)Z;

    const size_t need_full = (Z + (size_t)NTILE * 16384) - (char*)d_ws;   // ~92 MB
    const size_t need_r19  = (Z + (size_t)NBKT * CAP * 4) - (char*)d_ws;  // ~48 MB

    if (ws_size >= need_full) {
        w_to_bf16<<<(OUT_DIM * IN_DIM + 255) / 256, 256, 0, stream>>>(W, Wb, bcnt);
        cvt_bin<<<NBLK + NCVT, 512, 0, stream>>>(x, xswz, erow, ecol, eval, bcnt, gbuf);
        gemm_async<<<NGBLK, 512, 0, stream>>>(xswz, Wb, hb);
        sort_bucket<<<NBKT, 256, 0, stream>>>(gbuf, bcnt, gcsr, offs, bend);
        spmm_gather<<<N_NODES / 8, 256, 0, stream>>>(hb, offs, bend, gcsr, out);
    } else if (ws_size >= need_r19) {
        w_to_bf16<<<(OUT_DIM * IN_DIM + 255) / 256, 256, 0, stream>>>(W, Wb, bcnt);
        gemm_bin<<<NBLK + NGBLK, 512, 0, stream>>>(x, Wb, hb, erow, ecol, eval, bcnt, gbuf);
        sort_bucket<<<NBKT, 256, 0, stream>>>(gbuf, bcnt, gcsr, offs, bend);
        spmm_gather<<<N_NODES / 8, 256, 0, stream>>>(hb, offs, bend, gcsr, out);
    } else {
        gemm_plain<<<(N_NODES + 2 * BMT - 1) / (2 * BMT), 512, 0, stream>>>(x, W, hb);
        hipMemsetAsync(d_out, 0, (size_t)out_size * sizeof(float), stream);
        spmm_scatter<<<8192, 256, 0, stream>>>(hb, erow, ecol, eval, out);
    }
}

// Round 22
// 114.888 us; speedup vs baseline: 1.2707x; 1.2707x over previous
//
#include <hip/hip_runtime.h>
#include <hip/hip_fp16.h>

#define N_NODES 100000
#define N_EDGES 1600000
#define IN_DIM  256
#define OUT_DIM 128

#define BROWS  256                     // rows per bucket
#define NBKT   391                     // ceil(100000/256)
#define CAP    4608                    // per-bucket capacity (mean 4096 + 8 sigma)
#define CHUNK  8192                    // edges per bin block
#define NBLK   196                     // ceil(1600000/8192)
#define DCAP   6144                    // LDS sort capacity

#define BMT    32                      // pipelined gemm tile rows (16 KB bf16 LDS)
#define NTILE  (N_NODES / BMT)         // 3125 (exact)
#define TPB    4                       // tiles per gemm block
#define NGBLK  ((NTILE + TPB - 1) / TPB)   // 782
#define BUFSZ  (BMT * 512)

typedef __attribute__((ext_vector_type(8))) short short8;
typedef __attribute__((ext_vector_type(4))) float f32x4;
typedef __attribute__((ext_vector_type(2))) float f32x2;

// f32 -> bf16 round-to-nearest-even (bit trick)
__device__ __forceinline__ unsigned short f2bf(float f) {
    unsigned int u = __float_as_uint(f);
    u += 0x7FFFu + ((u >> 16) & 1u);
    return (unsigned short)(u >> 16);
}
__device__ __forceinline__ float bf2f(unsigned int u16) {
    return __uint_as_float(u16 << 16);
}

__device__ __forceinline__ short8 pack8(float4 a, float4 b) {
    short8 s;
    s[0] = (short)f2bf(a.x); s[1] = (short)f2bf(a.y);
    s[2] = (short)f2bf(a.z); s[3] = (short)f2bf(a.w);
    s[4] = (short)f2bf(b.x); s[5] = (short)f2bf(b.y);
    s[6] = (short)f2bf(b.z); s[7] = (short)f2bf(b.w);
    return s;
}

// ---------------------------------------------------------------------------
// W (f32 [128][256]) -> bf16, once; block 0 also zeros bcnt.
// ---------------------------------------------------------------------------
__global__ __launch_bounds__(256) void w_to_bf16(const float* __restrict__ W,
                                                 unsigned short* __restrict__ Wb,
                                                 int* __restrict__ bcnt) {
    int i = blockIdx.x * 256 + threadIdx.x;
    if (i < OUT_DIM * IN_DIM) Wb[i] = f2bf(W[i]);
    if (blockIdx.x == 0) {
        for (int b = threadIdx.x; b < NBKT; b += 256) bcnt[b] = 0;
    }
}

// ---------------------------------------------------------------------------
// Fused kernel (R19-proven, byte-identical): blocks [0,NBLK) = bin pass;
// blocks [NBLK, NBLK+NGBLK) = 4-tile pipelined MFMA GEMM.
// ---------------------------------------------------------------------------
__global__ __launch_bounds__(512) void gemm_bin(const float* __restrict__ x,
                                                const unsigned short* __restrict__ Wb,
                                                unsigned short* __restrict__ hb,
                                                const int* __restrict__ erow,
                                                const int* __restrict__ ecol,
                                                const float* __restrict__ eval,
                                                int* __restrict__ bcnt,
                                                int2* __restrict__ gbuf) {
    __shared__ unsigned short xs[2 * BMT * 256];   // 32 KB
    const int tid = threadIdx.x;

    if (blockIdx.x < NBLK) {
        // ------------------ bin role ------------------
        int* h    = (int*)xs;
        int* gpos = h + NBKT;
        int* rcur = gpos + NBKT;
        for (int i = tid; i < NBKT; i += 512) { h[i] = 0; rcur[i] = 0; }
        __syncthreads();
        const int e0 = blockIdx.x * CHUNK;
        for (int i = tid; i < CHUNK; i += 512) {
            int e = e0 + i;
            if (e < N_EDGES) atomicAdd(&h[erow[e] >> 8], 1);
        }
        __syncthreads();
        for (int i = tid; i < NBKT; i += 512)
            gpos[i] = h[i] ? (i * CAP + atomicAdd(&bcnt[i], h[i])) : 0;
        __syncthreads();
        for (int i = tid; i < CHUNK; i += 512) {
            int e = e0 + i;
            if (e < N_EDGES) {
                int r = erow[e];
                int b = r >> 8;
                unsigned int vb  = __half_as_ushort(__float2half(eval[e]));
                unsigned int rec = (vb << 17) | (unsigned int)ecol[e];
                int pos = gpos[b] + atomicAdd(&rcur[b], 1);
                gbuf[pos] = make_int2((int)rec, r);
            }
        }
        return;
    }

    // ------------------ gemm role: 4-tile pipelined (R19-proven) ------------------
    const int g    = blockIdx.x - NBLK;
    const int t0   = g * TPB;
    const int wid  = tid >> 6;
    const int lane = tid & 63;
    const int l15  = lane & 15;
    const int g8   = (lane >> 4) * 8;
    const int col  = wid * 16 + l15;
    const int sw   = (l15 & 7) << 4;
    char* lb = (char*)xs;

    const int srow = tid >> 4;
    const int ca   = (tid & 15) * 8;
    const int swr  = (srow & 7) << 4;
    const int wbA  = (srow * 512 + ca * 2) ^ swr;
    const int wbB  = (srow * 512 + (ca + 128) * 2) ^ swr;

    short8 bfr[8];
    const unsigned short* wrow = Wb + (size_t)col * IN_DIM + g8;
#pragma unroll
    for (int kk = 0; kk < 8; ++kk)
        bfr[kk] = *(const short8*)(wrow + kk * 32);

    // prologue: load + write tile t0 into buffer 0
    {
        const int ti = t0;
        const int gr = (ti < NTILE) ? (ti * BMT + srow) : srow;
        const float4* sA = (const float4*)(x + (size_t)gr * IN_DIM + ca);
        const float4* sB = (const float4*)(x + (size_t)gr * IN_DIM + ca + 128);
        float4 f0 = sA[0], f1 = sA[1], f2 = sB[0], f3 = sB[1];
        *(short8*)(lb + wbA) = pack8(f0, f1);
        *(short8*)(lb + wbB) = pack8(f2, f3);
    }

#pragma unroll
    for (int i = 0; i < TPB; ++i) {
        float4 q0, q1, q2, q3;
        if (i + 1 < TPB) {
            const int ti = t0 + i + 1;
            const int gr = (ti < NTILE) ? (ti * BMT + srow) : srow;
            const float4* sA = (const float4*)(x + (size_t)gr * IN_DIM + ca);
            const float4* sB = (const float4*)(x + (size_t)gr * IN_DIM + ca + 128);
            q0 = sA[0]; q1 = sA[1]; q2 = sB[0]; q3 = sB[1];
        }
        __syncthreads();

        const int ti = t0 + i;
        const char* cb = lb + (i & 1) * BUFSZ;
        short8 a0[8], a1[8];
#pragma unroll
        for (int kk = 0; kk < 8; ++kk) {
            a0[kk] = *(const short8*)(cb + ((l15 * 512 + (kk * 32 + g8) * 2) ^ sw));
            a1[kk] = *(const short8*)(cb + (((l15 + 16) * 512 + (kk * 32 + g8) * 2) ^ sw));
        }
        f32x4 acc0 = {0.f, 0.f, 0.f, 0.f}, acc1 = {0.f, 0.f, 0.f, 0.f};
#pragma unroll
        for (int kk = 0; kk < 8; ++kk) {
            acc0 = __builtin_amdgcn_mfma_f32_16x16x32_bf16(a0[kk], bfr[kk], acc0, 0, 0, 0);
            acc1 = __builtin_amdgcn_mfma_f32_16x16x32_bf16(a1[kk], bfr[kk], acc1, 0, 0, 0);
        }
        if (ti < NTILE) {
            const int rb0 = ti * BMT + (lane >> 4) * 4;
            const int rb1 = rb0 + 16;
#pragma unroll
            for (int q = 0; q < 4; ++q) {
                hb[(size_t)(rb0 + q) * OUT_DIM + col] = f2bf(acc0[q]);
                hb[(size_t)(rb1 + q) * OUT_DIM + col] = f2bf(acc1[q]);
            }
        }
        if (i + 1 < TPB) {
            char* wbuf = lb + ((i + 1) & 1) * BUFSZ;
            *(short8*)(wbuf + wbA) = pack8(q0, q1);
            *(short8*)(wbuf + wbB) = pack8(q2, q3);
        }
    }
}

// ---------------------------------------------------------------------------
// Per-bucket LDS counting sort, 512 threads (R20-validated-correct):
// hist -> scan (t<256, convergent barriers) -> ranked scatter -> writeout.
// ---------------------------------------------------------------------------
__global__ __launch_bounds__(512) void sort_bucket(const int2* __restrict__ gbuf,
                                                   const int* __restrict__ bcnt,
                                                   unsigned int* __restrict__ gcsr,
                                                   int* __restrict__ offs,
                                                   int* __restrict__ bend) {
    __shared__ int rh[BROWS], rc[BROWS], tmp[256];
    __shared__ unsigned int lout[DCAP];
    const int b    = blockIdx.x;
    const int base = b * CAP;
    const int cnt  = bcnt[b];
    const int r0   = b * BROWS;
    const int t    = threadIdx.x;

    if (t < BROWS) rh[t] = 0;
    __syncthreads();
    for (int i = t; i < cnt; i += 512)
        atomicAdd(&rh[gbuf[base + i].y - r0], 1);
    __syncthreads();

    int v = (t < 256) ? rh[t] : 0;
    if (t < 256) tmp[t] = v;
    __syncthreads();
    for (int d = 1; d < 256; d <<= 1) {
        int a = (t < 256 && t >= d) ? tmp[t - d] : 0;
        __syncthreads();
        if (t < 256) tmp[t] += a;
        __syncthreads();
    }
    if (t < 256) {
        int ex = tmp[t] - v;
        rc[t] = ex;
        offs[r0 + t] = base + ex;
    }
    if (t == 0) bend[b] = base + cnt;
    __syncthreads();

    if (cnt <= DCAP) {
        for (int i = t; i < cnt; i += 512) {
            int2 rr = gbuf[base + i];
            int p = atomicAdd(&rc[rr.y - r0], 1);
            lout[p] = (unsigned int)rr.x;
        }
        __syncthreads();
        for (int i = t; i < cnt; i += 512)
            gcsr[base + i] = lout[i];
    } else {  // unreachable (cnt <= CAP < DCAP); correctness fallback
        for (int i = t; i < cnt; i += 512) {
            int2 rr = gbuf[base + i];
            int p = atomicAdd(&rc[rr.y - r0], 1);
            gcsr[base + p] = (unsigned int)rr.x;
        }
    }
}

// ---------------------------------------------------------------------------
// Gather: 4 rows per wave (one per 16-lane quarter), lane owns 8 channels
// via uint4 (16B) hb loads -> 2x outstanding bytes vs uint2 version.
// Grid 6250 x 256 thr = exactly 100000 rows.
// ---------------------------------------------------------------------------
__global__ __launch_bounds__(256) void spmm_gather(const unsigned short* __restrict__ hb,
                                                   const int* __restrict__ offs,
                                                   const int* __restrict__ bend,
                                                   const unsigned int* __restrict__ ccv,
                                                   float* __restrict__ out) {
    const int lane = threadIdx.x & 63;
    const int qtr  = lane >> 4;                 // 0..3 (row within wave)
    const int li   = lane & 15;                 // lane in quarter
    const int r    = blockIdx.x * 16 + (threadIdx.x >> 6) * 4 + qtr;

    const int js = offs[r];
    const int je = ((r & (BROWS - 1)) == (BROWS - 1)) ? bend[r >> 8] : offs[r + 1];

    f32x2 acc0 = {0.f, 0.f}, acc1 = {0.f, 0.f};
    f32x2 acc2 = {0.f, 0.f}, acc3 = {0.f, 0.f};
    for (int j = js; __any(j < je); j += 8) {
        unsigned int e[8];
        uint4 p[8];
#pragma unroll
        for (int q = 0; q < 8; ++q) {
            int jj = j + q;
            e[q] = ccv[jj < je ? jj : 0];
        }
#pragma unroll
        for (int q = 0; q < 8; ++q)
            p[q] = *(const uint4*)(hb + (size_t)(e[q] & 0x1FFFFu) * OUT_DIM + li * 8);
#pragma unroll
        for (int q = 0; q < 8; ++q) {
            float v = (j + q < je)
                    ? __half2float(__ushort_as_half((unsigned short)(e[q] >> 17)))
                    : 0.f;
            f32x2 vv = {v, v};
            f32x2 h01 = { __uint_as_float(p[q].x << 16), __uint_as_float(p[q].x & 0xFFFF0000u) };
            f32x2 h23 = { __uint_as_float(p[q].y << 16), __uint_as_float(p[q].y & 0xFFFF0000u) };
            f32x2 h45 = { __uint_as_float(p[q].z << 16), __uint_as_float(p[q].z & 0xFFFF0000u) };
            f32x2 h67 = { __uint_as_float(p[q].w << 16), __uint_as_float(p[q].w & 0xFFFF0000u) };
            acc0 = __builtin_elementwise_fma(vv, h01, acc0);
            acc1 = __builtin_elementwise_fma(vv, h23, acc1);
            acc2 = __builtin_elementwise_fma(vv, h45, acc2);
            acc3 = __builtin_elementwise_fma(vv, h67, acc3);
        }
    }
    float4 o0 = {acc0.x, acc0.y, acc1.x, acc1.y};
    float4 o1 = {acc2.x, acc2.y, acc3.x, acc3.y};
    float* dst = out + (size_t)r * OUT_DIM + li * 8;
    *(float4*)dst       = o0;
    *(float4*)(dst + 4) = o1;
}

// ---------------------------------------------------------------------------
// Fallback path (workspace too small): plain gemm + atomic scatter.
// ---------------------------------------------------------------------------
__global__ __launch_bounds__(512) void gemm_plain(const float* __restrict__ x,
                                                  const float* __restrict__ W,
                                                  unsigned short* __restrict__ hb) {
    __shared__ unsigned short xs[2 * BMT * 256];
    const int tid = threadIdx.x;
    const int m0  = blockIdx.x * (2 * BMT);
    char* lb = (char*)xs;
    {
        const int row = tid >> 3;
        const int cs  = (tid & 7) * 32;
        const int gr  = m0 + row;
        if (gr < N_NODES) {
            const float4* src = (const float4*)(x + (size_t)gr * IN_DIM + cs);
#pragma unroll
            for (int i = 0; i < 4; ++i) {
                float4 a = src[2 * i], b = src[2 * i + 1];
                int byt = (row * 512 + (cs + 8 * i) * 2) ^ ((row & 7) << 4);
                *(short8*)(lb + byt) = pack8(a, b);
            }
        } else {
            short8 z = {0, 0, 0, 0, 0, 0, 0, 0};
#pragma unroll
            for (int i = 0; i < 4; ++i) {
                int byt = (row * 512 + (cs + 8 * i) * 2) ^ ((row & 7) << 4);
                *(short8*)(lb + byt) = z;
            }
        }
    }
    __syncthreads();
    const int wid  = tid >> 6;
    const int lane = tid & 63;
    const int l15  = lane & 15;
    const int g8   = (lane >> 4) * 8;
    short8 bfr[8];
    const float* wrowf = W + (size_t)(wid * 16 + l15) * IN_DIM + g8;
#pragma unroll
    for (int kk = 0; kk < 8; ++kk) {
        float4 wa = *(const float4*)(wrowf + kk * 32);
        float4 wb = *(const float4*)(wrowf + kk * 32 + 4);
        bfr[kk] = pack8(wa, wb);
    }
    const int col = wid * 16 + l15;
    const int sw  = (l15 & 7) << 4;
    const char* lbc = (const char*)xs;
#pragma unroll
    for (int rp = 0; rp < 2; ++rp) {
        const int r0 = rp * 32 + l15;
        const int r1 = r0 + 16;
        short8 a0[8], a1[8];
#pragma unroll
        for (int kk = 0; kk < 8; ++kk) {
            a0[kk] = *(const short8*)(lbc + ((r0 * 512 + (kk * 32 + g8) * 2) ^ sw));
            a1[kk] = *(const short8*)(lbc + ((r1 * 512 + (kk * 32 + g8) * 2) ^ sw));
        }
        f32x4 acc0 = {0.f, 0.f, 0.f, 0.f}, acc1 = {0.f, 0.f, 0.f, 0.f};
#pragma unroll
        for (int kk = 0; kk < 8; ++kk) {
            acc0 = __builtin_amdgcn_mfma_f32_16x16x32_bf16(a0[kk], bfr[kk], acc0, 0, 0, 0);
            acc1 = __builtin_amdgcn_mfma_f32_16x16x32_bf16(a1[kk], bfr[kk], acc1, 0, 0, 0);
        }
        const int rb0 = m0 + rp * 32 + (lane >> 4) * 4;
        const int rb1 = rb0 + 16;
#pragma unroll
        for (int i = 0; i < 4; ++i) {
            if (rb0 + i < N_NODES) hb[(size_t)(rb0 + i) * OUT_DIM + col] = f2bf(acc0[i]);
            if (rb1 + i < N_NODES) hb[(size_t)(rb1 + i) * OUT_DIM + col] = f2bf(acc1[i]);
        }
    }
}

__global__ __launch_bounds__(256) void spmm_scatter(const unsigned short* __restrict__ hb,
                                                    const int* __restrict__ erow,
                                                    const int* __restrict__ ecol,
                                                    const float* __restrict__ eval,
                                                    float* __restrict__ out) {
    const int lane = threadIdx.x & 63;
    const int eloc = threadIdx.x >> 6;
    const int stride = gridDim.x * 4;
    for (int e = blockIdx.x * 4 + eloc; e < N_EDGES; e += stride) {
        const int r = erow[e];
        const int c = ecol[e];
        const float v = eval[e];
        unsigned int p = *(const unsigned int*)(hb + (size_t)c * OUT_DIM + lane * 2);
        float* o = out + (size_t)r * OUT_DIM + lane * 2;
        unsafeAtomicAdd(o + 0, v * bf2f(p & 0xFFFFu));
        unsafeAtomicAdd(o + 1, v * bf2f(p >> 16));
    }
}

extern "C" void kernel_launch(void* const* d_in, const int* in_sizes, int n_in,
                              void* d_out, int out_size, void* d_ws, size_t ws_size,
                              hipStream_t stream) {
    const float* x    = (const float*)d_in[0];
    const float* W    = (const float*)d_in[1];
    const int*   erow = (const int*)d_in[2];
    const int*   ecol = (const int*)d_in[3];
    const float* eval = (const float*)d_in[4];
    float*       out  = (float*)d_out;

    // workspace layout (8B-aligned boundaries)
    const size_t H_ELEMS = (size_t)N_NODES * OUT_DIM;            // 12.8M
    unsigned short* hb    = (unsigned short*)d_ws;               // 25.6 MB
    int2*           gbuf  = (int2*)(hb + H_ELEMS);               // NBKT*CAP int2 (14.4 MB)
    unsigned int*   gcsr  = (unsigned int*)(gbuf + (size_t)NBKT * CAP);  // 7.2 MB
    int*            offs  = (int*)(gcsr + (size_t)NBKT * CAP);   // NBKT*BROWS ints
    int*            bend  = offs + NBKT * BROWS + 8;             // NBKT
    int*            bcnt  = bend + NBKT;                         // NBKT
    unsigned short* Wb    = (unsigned short*)(bcnt + NBKT + 8);  // 32768 bf16
    const size_t need = ((char*)(Wb + OUT_DIM * IN_DIM)) - (char*)d_ws;  // ~47.8 MB

    if (ws_size >= need) {
        w_to_bf16<<<(OUT_DIM * IN_DIM + 255) / 256, 256, 0, stream>>>(W, Wb, bcnt);
        gemm_bin<<<NBLK + NGBLK, 512, 0, stream>>>(x, Wb, hb, erow, ecol, eval, bcnt, gbuf);
        sort_bucket<<<NBKT, 512, 0, stream>>>(gbuf, bcnt, gcsr, offs, bend);
        spmm_gather<<<N_NODES / 16, 256, 0, stream>>>(hb, offs, bend, gcsr, out);
    } else {
        gemm_plain<<<(N_NODES + 2 * BMT - 1) / (2 * BMT), 512, 0, stream>>>(x, W, hb);
        hipMemsetAsync(d_out, 0, (size_t)out_size * sizeof(float), stream);
        spmm_scatter<<<8192, 256, 0, stream>>>(hb, erow, ecol, eval, out);
    }
}